// Round 15
// baseline (86.610 us; speedup 1.0000x reference)
//
#include <hip/hip_runtime.h>
#include <hip/hip_bf16.h>
#include <stdint.h>

// Upsample2x(nearest) + Conv3x3(pad1) + bias via the parity trick:
//   out[b,co,2r+py,2s+px] = bias[co] +
//     sum_{ky,kx in {0,1}, ci} weff[py,px][co][ky,kx,ci] * xpad[b, r+py+ky, s+px+kx, ci]
// 4 parity GEMMs: M=512(co) x N=8192(b,r,s) x K=2048.
// R15: 4 waves (2Mx2N), each 128x128 (acc 8x8) -> A/B frag duplication x2
// instead of x4/x2: LDS traffic 96KB per BK-32 tile (750-1130cy) < MFMA
// (1242cy) -> MFMA-bound. BM=BN=256, BK=32, 4-slot LDS ring (128KB), stage
// distance 2 tiles, 1 barrier + GATE(16) per tile. Folded LDS layout:
// 128 rows x 128B holding co/n halves {r, r+128} in 8 16B slots, phys slot =
// logical ^ (row&7), swizzle on BOTH staging source and ds_read (rule #21).

typedef __attribute__((ext_vector_type(8)))  __bf16 bf16x8;
typedef __attribute__((ext_vector_type(4)))  float  f32x4;
typedef __attribute__((ext_vector_type(4)))  int    int4v;

__device__ __forceinline__ void async16(const void* g, void* l) {
  __builtin_amdgcn_global_load_lds(
      (const __attribute__((address_space(1))) void*)g,
      (__attribute__((address_space(3))) void*)l,
      16, 0, 0);
}

// ---------------------------------------------------------------------------
// fused_prep: grid = 3336 blocks x 256 threads (unchanged from R8)
__global__ void fused_prep(const float* __restrict__ x,
                           const float* __restrict__ w,
                           __hip_bfloat16* __restrict__ xpad,
                           __hip_bfloat16* __restrict__ weff) {
  const int bid = blockIdx.x;
  const int tid = threadIdx.x;
  __shared__ __align__(16) __hip_bfloat16 ldsT[32][80];

  if (bid < 2048) {
    const int blk = bid;
    const int cib = blk & 7;
    const int r   = (blk >> 3) & 31;
    const int b   = blk >> 8;
    const int ci_l = tid >> 2;
    const int wq   = tid & 3;
    const float* xp = x + (((size_t)(b * 512 + cib * 64 + ci_l) * 32 + r) * 32) + wq * 8;
    float4 v0 = *(const float4*)(xp);
    float4 v1 = *(const float4*)(xp + 4);
    const int wb = wq * 8;
    ldsT[wb + 0][ci_l] = __float2bfloat16(v0.x);
    ldsT[wb + 1][ci_l] = __float2bfloat16(v0.y);
    ldsT[wb + 2][ci_l] = __float2bfloat16(v0.z);
    ldsT[wb + 3][ci_l] = __float2bfloat16(v0.w);
    ldsT[wb + 4][ci_l] = __float2bfloat16(v1.x);
    ldsT[wb + 5][ci_l] = __float2bfloat16(v1.y);
    ldsT[wb + 6][ci_l] = __float2bfloat16(v1.z);
    ldsT[wb + 7][ci_l] = __float2bfloat16(v1.w);
    __syncthreads();
    const int w_o = tid >> 3;
    const int ch  = tid & 7;
    char* dst = (char*)xpad +
        ((((size_t)(b * 34 + (r + 1)) * 34) + (w_o + 1)) * 512 + cib * 64 + ch * 8) * 2;
    *(int4v*)dst = *(const int4v*)&ldsT[w_o][ch * 8];
  } else if (bid < 3072) {
    const int idx = (bid - 2048) * 256 + tid;
    const float* wp = w + (size_t)idx * 9;
    const int co = idx >> 9;
    const int ci = idx & 511;
    float t[9];
#pragma unroll
    for (int i = 0; i < 9; ++i) t[i] = wp[i];
#pragma unroll
    for (int py = 0; py < 2; ++py) {
#pragma unroll
      for (int px = 0; px < 2; ++px) {
        const int p = py * 2 + px;
#pragma unroll
        for (int ky = 0; ky < 2; ++ky) {
          const int ulo = (ky == 0) ? 0 : (py == 0 ? 1 : 2);
          const int uhi = (ky == 0) ? (py == 0 ? 0 : 1) : 2;
#pragma unroll
          for (int kx = 0; kx < 2; ++kx) {
            const int vlo = (kx == 0) ? 0 : (px == 0 ? 1 : 2);
            const int vhi = (kx == 0) ? (px == 0 ? 0 : 1) : 2;
            float s = 0.f;
            for (int u = ulo; u <= uhi; ++u)
              for (int v = vlo; v <= vhi; ++v)
                s += t[u * 3 + v];
            const int kk = ky * 2 + kx;
            weff[(((size_t)p * 512 + co) * 4 + kk) * 512 + ci] = __float2bfloat16(s);
          }
        }
      }
    }
  } else if (bid < 3208) {
    const int f  = (bid - 3072) * 2048 + tid * 8;
    const int b  = f / 34816;
    const int rr = (f / 17408) & 1;
    const int off = f % 17408;
    __hip_bfloat16* dst = xpad + ((size_t)(b * 34 + rr * 33) * 17408) + off;
    int4v z = {0, 0, 0, 0};
    *(int4v*)dst = z;
  } else {
    const int f  = (bid - 3208) * 2048 + tid * 8;
    const int b  = f / 32768;
    const int cc = (f / 16384) & 1;
    const int r  = ((f / 512) & 31) + 1;
    const int ci = f & 511;
    __hip_bfloat16* dst = xpad +
        (((size_t)(b * 34 + r) * 34) + cc * 33) * 512 + ci;
    int4v z = {0, 0, 0, 0};
    *(int4v*)dst = z;
  }
}

// ---------------------------------------------------------------------------
// GEMM. LDS ring: slot d (d=0..3): A @ d*16384, B @ 65536 + d*16384.
// Each 16KB = 128 rows x 128B; row r holds {co0+r (slots 0-3), co0+r+128
// (slots 4-7)} x 4 K-chunks of 8 bf16; phys slot = logical ^ (r&7).
#define MM(a, b, c) __builtin_amdgcn_mfma_f32_16x16x32_bf16((a), (b), (c), 0, 0, 0)
#define BAR() asm volatile("s_barrier" ::: "memory")
#define PRIO(x) __builtin_amdgcn_s_setprio(x)
#define GATE(N) asm volatile("s_waitcnt vmcnt(" N ")" ::: "memory")

// B k-tile offset in xpad elements: kk=(ky,kx) block + ci chunk
#define OFFB_B(T) ((((T) >> 5) * 34 + (((T) >> 4) & 1)) * 512 + ((T) & 15) * 32)

// Stage tile T (A 16KB + B 16KB) into slot d: 8 async16/thread.
#define ST_T(T, d) do {                                                        \
    const size_t _ta = (size_t)(T) * 32;                                       \
    const int _ob = OFFB_B(T);                                                 \
    char* _la = lds + (d) * 16384 + dA;                                        \
    char* _lb = lds + 65536 + (d) * 16384 + dA;                                \
    async16(pA + _ta,          _la);          async16(pB + _ob,         _lb);  \
    async16(pA + _ta + 65536,  _la + 4096);   async16(pB + _ob + 17408, _lb + 4096); \
    async16(pA + _ta + 131072, _la + 8192);   async16(pB + _ob + 34816, _lb + 8192); \
    async16(pA + _ta + 196608, _la + 12288);  async16(pB + _ob + 52224, _lb + 12288); \
  } while (0)

// Read tile frags (A 8 m-blocks, B 8 n-blocks) from slot rs.
#define RD_AB(A, B, rs) do {                                                   \
    const char* _a = lds + (rs) * 16384 + aoffA;                               \
    const char* _b = lds + 65536 + (rs) * 16384 + aoffB;                       \
    _Pragma("unroll") for (int _m = 0; _m < 8; ++_m)                           \
      (A)[_m] = *(const bf16x8*)(_a + _m * 2048);                              \
    _Pragma("unroll") for (int _n = 0; _n < 8; ++_n)                           \
      (B)[_n] = *(const bf16x8*)(_b + _n * 2048);                              \
  } while (0)

#define MFMA64(A, B) do {                                                      \
    _Pragma("unroll") for (int _m = 0; _m < 8; ++_m)                           \
      _Pragma("unroll") for (int _n = 0; _n < 8; ++_n)                         \
        acc[_m][_n] = MM((A)[_m], (B)[_n], acc[_m][_n]);                       \
  } while (0)

// One tile: RD(T+1) [staging forced by prev tile's gate+barrier] | MFMA(T) |
// ST(T+4, slot T&3) [>=1 barrier after all waves consumed slot's old data] |
// GATE forces T+2 for next tile's RD | BAR.
#define TILE(T, rs, AC, BC, AN, BN, DOST, G) do {                              \
    RD_AB(AN, BN, rs);                                                         \
    PRIO(1); MFMA64(AC, BC); PRIO(0);                                          \
    if (DOST) ST_T((T) + 4, (T) & 3);                                          \
    GATE(G); BAR();                                                            \
  } while (0)

__global__ __launch_bounds__(256, 1) void upconv_gemm(
    const __hip_bfloat16* __restrict__ xpad,   // [8][34][34][512]
    const __hip_bfloat16* __restrict__ weff,   // [4][512][2048]
    const float* __restrict__ bias,
    float* __restrict__ out) {                 // [8][512][64][64]
  extern __shared__ __align__(16) char lds[]; // 131072 B

  // px-twin XCD map (same as R12).
  const int bid = blockIdx.x;
  const int g = bid & 7, i = bid >> 3;
  const int py = g >> 2;
  const int mt = (g >> 1) & 1;
  const int nh = g & 1;
  const int px = i & 1;
  const int nt = nh * 16 + (i >> 1);   // 0..31
  const int p  = py * 2 + px;
  const int co0 = mt << 8;
  const int n0  = nt << 8;
  const int b   = n0 >> 10;
  const int rb  = (n0 & 1023) >> 5;    // 0,8,16,24

  const int tid  = threadIdx.x;
  const int lane = tid & 63;
  const int wv   = tid >> 6;           // 0..3
  const int wr   = wv >> 1;            // M half (128 rows)
  const int wc   = wv & 1;             // N half (128 cols)

  // ---- staging: thread covers LDS rows srow+32k (k=0..3), phys slot tid&7,
  // logical sl = (tid&7)^(srow&7). Logical slot encodes {half: sl>>2,
  // K-chunk: sl&3}.
  const int srow = tid >> 3;           // 0..31
  const int sl   = (tid & 7) ^ (srow & 7);
  const int dA   = wv * 1024;          // wave rows 8wv.. (+32k via +4096)

  const __hip_bfloat16* pA = weff + ((size_t)p << 20)
      + (size_t)(co0 + srow + (sl >> 2) * 128) * 2048 + (sl & 3) * 8;
  const __hip_bfloat16* pB = xpad +
      ((size_t)(b * 34 + rb + (sl >> 2) * 4 + py) * 34 + srow + px) * 512
      + (sl & 3) * 8;

  // ---- frag ds_read addressing: row = blk*16 + (lane&15), half = wr/wc,
  // logical = (lane>>4) | (half<<2), phys = logical ^ (row&7) = ^ (lane&7).
  const int aoffA = (lane & 15) * 128
      + ((((lane >> 4) | (wr << 2)) ^ (lane & 7)) * 16);
  const int aoffB = (lane & 15) * 128
      + ((((lane >> 4) | (wc << 2)) ^ (lane & 7)) * 16);

  f32x4 acc[8][8] = {};                 // 256 regs (AGPR side)
  bf16x8 Ae[8], Be[8], Ao[8], Bo[8];    // E/O frag sets, 128 regs

  // ---- prologue: stage tiles 0..3 (32 loads); force {0,1}; read tile 0.
  ST_T(0, 0); ST_T(1, 1); ST_T(2, 2); ST_T(3, 3);
  GATE("16"); BAR();
  RD_AB(Ae, Be, 0);

  // ---- 64 K-tiles of BK=32. Steady: ST(T+4), GATE(16) forces T+2.
#pragma unroll 1
  for (int t = 0; t < 60; t += 4) {
    TILE(t + 0, (t + 1) & 3, Ae, Be, Ao, Bo, true, "16");
    TILE(t + 1, (t + 2) & 3, Ao, Bo, Ae, Be, true, "16");
    TILE(t + 2, (t + 3) & 3, Ae, Be, Ao, Bo, true, "16");
    TILE(t + 3, (t + 4) & 3, Ao, Bo, Ae, Be, true, "16");
  }
  // tails: tiles 60..63 (no staging; gates force 62, then 63)
  TILE(60, 1, Ae, Be, Ao, Bo, false, "8");
  TILE(61, 2, Ao, Bo, Ae, Be, false, "0");
  TILE(62, 3, Ae, Be, Ao, Bo, false, "0");
  PRIO(1); MFMA64(Ao, Bo); PRIO(0);   // tile 63

  // ---- epilogue: D layout row=(lane>>4)*4+j, col=lane&15 (m89)
#pragma unroll
  for (int m = 0; m < 8; ++m) {
    const int coB = co0 + wr * 128 + m * 16 + ((lane >> 4) << 2);
    float bv[4];
#pragma unroll
    for (int j = 0; j < 4; ++j) bv[j] = bias[coB + j];
#pragma unroll
    for (int nn = 0; nn < 8; ++nn) {
      const int nl = wc * 128 + nn * 16 + (lane & 15);
      const int rr = rb + (nl >> 5);
      const int ss = nl & 31;
      const int oh = rr * 2 + py;
      const int ow = ss * 2 + px;
      float* op = out + (((size_t)(b * 512 + coB) << 6) + oh) * 64 + ow;
#pragma unroll
      for (int j = 0; j < 4; ++j)
        op[(size_t)j * 4096] = acc[m][nn][j] + bv[j];
    }
  }
}

// ---------------------------------------------------------------------------
extern "C" void kernel_launch(void* const* d_in, const int* in_sizes, int n_in,
                              void* d_out, int out_size, void* d_ws, size_t ws_size,
                              hipStream_t stream) {
  (void)in_sizes; (void)n_in; (void)out_size; (void)ws_size;
  const float* x  = (const float*)d_in[0];   // [8][512][32][32]
  const float* w  = (const float*)d_in[1];   // [512][512][3][3]
  const float* bs = (const float*)d_in[2];   // [512]
  float* out = (float*)d_out;                // [8][512][64][64]
  char* ws = (char*)d_ws;
  __hip_bfloat16* xpad = (__hip_bfloat16*)ws;                 // 9,467,904 B
  __hip_bfloat16* weff = (__hip_bfloat16*)(ws + (10u << 20)); // 8,388,608 B
  fused_prep<<<dim3(3336), dim3(256), 0, stream>>>(x, w, xpad, weff);
  upconv_gemm<<<dim3(256), dim3(256), 131072, stream>>>(xpad, weff, bs, out);
}

// Round 16
// 83.907 us; speedup vs baseline: 1.0322x; 1.0322x over previous
//
#include <hip/hip_runtime.h>
#include <hip/hip_bf16.h>
#include <stdint.h>

// Upsample2x(nearest) + Conv3x3(pad1) + bias via the parity trick:
//   out[b,co,2r+py,2s+px] = bias[co] +
//     sum_{ky,kx in {0,1}, ci} weff[py,px][co][ky,kx,ci] * xpad[b, r+py+ky, s+px+kx, ci]
// 4 parity GEMMs: M=512(co) x N=8192(b,r,s) x K=2048.
// R16 = R12 skeleton (best schedule family) with MFMA 32x32x16 instead of
// 16x16x32: same FLOPs in 15% less matrix-pipe time (m119: 2495 vs 2176 TF),
// half the issue slots. LDS layout/swizzle/staging/gates identical; only
// frag indexing (4 k16-slots), acc type (f32x16), and epilogue C/D layout
// (col=lane&31, row=(reg&3)+8*(reg>>2)+4*(lane>>5), m74/m101) change.

typedef __attribute__((ext_vector_type(8)))  __bf16 bf16x8;
typedef __attribute__((ext_vector_type(16))) float  f32x16;
typedef __attribute__((ext_vector_type(4)))  int    int4v;

__device__ __forceinline__ void async16(const void* g, void* l) {
  __builtin_amdgcn_global_load_lds(
      (const __attribute__((address_space(1))) void*)g,
      (__attribute__((address_space(3))) void*)l,
      16, 0, 0);
}

// ---------------------------------------------------------------------------
// fused_prep: grid = 3336 blocks x 256 threads (unchanged from R8)
__global__ void fused_prep(const float* __restrict__ x,
                           const float* __restrict__ w,
                           __hip_bfloat16* __restrict__ xpad,
                           __hip_bfloat16* __restrict__ weff) {
  const int bid = blockIdx.x;
  const int tid = threadIdx.x;
  __shared__ __align__(16) __hip_bfloat16 ldsT[32][80];

  if (bid < 2048) {
    const int blk = bid;
    const int cib = blk & 7;
    const int r   = (blk >> 3) & 31;
    const int b   = blk >> 8;
    const int ci_l = tid >> 2;
    const int wq   = tid & 3;
    const float* xp = x + (((size_t)(b * 512 + cib * 64 + ci_l) * 32 + r) * 32) + wq * 8;
    float4 v0 = *(const float4*)(xp);
    float4 v1 = *(const float4*)(xp + 4);
    const int wb = wq * 8;
    ldsT[wb + 0][ci_l] = __float2bfloat16(v0.x);
    ldsT[wb + 1][ci_l] = __float2bfloat16(v0.y);
    ldsT[wb + 2][ci_l] = __float2bfloat16(v0.z);
    ldsT[wb + 3][ci_l] = __float2bfloat16(v0.w);
    ldsT[wb + 4][ci_l] = __float2bfloat16(v1.x);
    ldsT[wb + 5][ci_l] = __float2bfloat16(v1.y);
    ldsT[wb + 6][ci_l] = __float2bfloat16(v1.z);
    ldsT[wb + 7][ci_l] = __float2bfloat16(v1.w);
    __syncthreads();
    const int w_o = tid >> 3;
    const int ch  = tid & 7;
    char* dst = (char*)xpad +
        ((((size_t)(b * 34 + (r + 1)) * 34) + (w_o + 1)) * 512 + cib * 64 + ch * 8) * 2;
    *(int4v*)dst = *(const int4v*)&ldsT[w_o][ch * 8];
  } else if (bid < 3072) {
    const int idx = (bid - 2048) * 256 + tid;
    const float* wp = w + (size_t)idx * 9;
    const int co = idx >> 9;
    const int ci = idx & 511;
    float t[9];
#pragma unroll
    for (int i = 0; i < 9; ++i) t[i] = wp[i];
#pragma unroll
    for (int py = 0; py < 2; ++py) {
#pragma unroll
      for (int px = 0; px < 2; ++px) {
        const int p = py * 2 + px;
#pragma unroll
        for (int ky = 0; ky < 2; ++ky) {
          const int ulo = (ky == 0) ? 0 : (py == 0 ? 1 : 2);
          const int uhi = (ky == 0) ? (py == 0 ? 0 : 1) : 2;
#pragma unroll
          for (int kx = 0; kx < 2; ++kx) {
            const int vlo = (kx == 0) ? 0 : (px == 0 ? 1 : 2);
            const int vhi = (kx == 0) ? (px == 0 ? 0 : 1) : 2;
            float s = 0.f;
            for (int u = ulo; u <= uhi; ++u)
              for (int v = vlo; v <= vhi; ++v)
                s += t[u * 3 + v];
            const int kk = ky * 2 + kx;
            weff[(((size_t)p * 512 + co) * 4 + kk) * 512 + ci] = __float2bfloat16(s);
          }
        }
      }
    }
  } else if (bid < 3208) {
    const int f  = (bid - 3072) * 2048 + tid * 8;
    const int b  = f / 34816;
    const int rr = (f / 17408) & 1;
    const int off = f % 17408;
    __hip_bfloat16* dst = xpad + ((size_t)(b * 34 + rr * 33) * 17408) + off;
    int4v z = {0, 0, 0, 0};
    *(int4v*)dst = z;
  } else {
    const int f  = (bid - 3208) * 2048 + tid * 8;
    const int b  = f / 32768;
    const int cc = (f / 16384) & 1;
    const int r  = ((f / 512) & 31) + 1;
    const int ci = f & 511;
    __hip_bfloat16* dst = xpad +
        (((size_t)(b * 34 + r) * 34) + cc * 33) * 512 + ci;
    int4v z = {0, 0, 0, 0};
    *(int4v*)dst = z;
  }
}

// ---------------------------------------------------------------------------
// GEMM. LDS: A slot d @ d*32768, B @ 65536 + d*32768. Row layout: [rows][8 x
// 16B slots], phys slot = logical ^ (row&7); swizzle on BOTH sides (rule #21).
#define MM32(a, b, c) __builtin_amdgcn_mfma_f32_32x32x16_bf16((a), (b), (c), 0, 0, 0)
#define BAR() asm volatile("s_barrier" ::: "memory")
#define PRIO(x) __builtin_amdgcn_s_setprio(x)
#define GATE(N) asm volatile("s_waitcnt vmcnt(" N ")" ::: "memory")

#define ST_A(T, d) do {                                                        \
    char* _l = lds + (d) * 32768 + dA;                                         \
    const __hip_bfloat16* _g = pA0 + (size_t)(T) * 64;                         \
    async16(_g, _l); async16(_g + 131072, _l + 8192);                          \
    async16(_g + 262144, _l + 16384); async16(_g + 393216, _l + 24576);        \
  } while (0)

#define OFFB(T) (((((T) >> 4) * 34) + (((T) >> 3) & 1)) * 512 + ((T) & 7) * 64)
#define ST_B(T, d) do {                                                        \
    char* _l = lds + 65536 + (d) * 32768 + dA;                                 \
    const int _o = OFFB(T);                                                    \
    async16(pB00 + _o, _l); async16(pB01 + _o, _l + 8192);                     \
    async16(pB10 + _o, _l + 16384); async16(pB11 + _o, _l + 24576);            \
  } while (0)

// A frags for M-pair mb (mb in {0,2}): D[m*4+q] = A-block (mb+m), k16-slot q.
#define RD_A(D, S, mb) do {                                                    \
    _Pragma("unroll") for (int _m = 0; _m < 2; ++_m)                           \
      _Pragma("unroll") for (int _q = 0; _q < 4; ++_q)                         \
        (D)[_m * 4 + _q] = *(const bf16x8*)((S) + ((mb) + _m) * 4096 + aq[_q]); \
  } while (0)

// B frags for n32-block nb: D[q].
#define RD_B(D, S, nb) do {                                                    \
    _Pragma("unroll") for (int _q = 0; _q < 4; ++_q)                           \
      (D)[_q] = *(const bf16x8*)((S) + (nb) * 4096 + aq[_q]);                  \
  } while (0)

// Quadrant: M-pair mb x n32-block nb over 4 k16 slices (8 MFMA-32).
#define MFMAQ(mb, nb, A, B) do {                                               \
    _Pragma("unroll") for (int _q = 0; _q < 4; ++_q)                           \
      _Pragma("unroll") for (int _m = 0; _m < 2; ++_m)                         \
        acc[(mb) + _m][nb] = MM32((A)[_m * 4 + _q], (B)[_q], acc[(mb) + _m][nb]); \
  } while (0)

// ---- Read-first variant (R8 order): ds_reads lead each phase.
#define ITER_RF(T, SE, SO, GE, GO, LAST) do {                                  \
  /* even tile: slot0 */                                                       \
  RD_A(Ab, aS0, 2);                                                            \
  PRIO(1); MFMAQ(0, 0, Aa, Ba); PRIO(0);                                       \
  RD_B(Bb, bS0, 1);                                                            \
  PRIO(1); MFMAQ(2, 0, Ab, Ba); PRIO(0);                                       \
  BAR();                                                                       \
  if (SE) ST_A((T) + 2, 0);                                                    \
  PRIO(1); MFMAQ(2, 1, Ab, Bb); PRIO(0);                                       \
  GATE(GE); BAR();                                                             \
  RD_A(Ab, aS1, 0); RD_B(Ba, bS1, 0);                                          \
  if (SE) ST_B((T) + 2, 0);                                                    \
  PRIO(1); MFMAQ(0, 1, Aa, Bb); PRIO(0);                                       \
  /* odd tile: slot1 */                                                        \
  RD_A(Aa, aS1, 2);                                                            \
  PRIO(1); MFMAQ(0, 0, Ab, Ba); PRIO(0);                                       \
  RD_B(Bb, bS1, 1);                                                            \
  PRIO(1); MFMAQ(2, 0, Aa, Ba); PRIO(0);                                       \
  BAR();                                                                       \
  if (SO) ST_A((T) + 3, 1);                                                    \
  PRIO(1); MFMAQ(2, 1, Aa, Bb); PRIO(0);                                       \
  GATE(GO); BAR();                                                             \
  if (!LAST) { RD_A(Aa, aS0, 0); RD_B(Ba, bS0, 0); }                           \
  if (SO) ST_B((T) + 3, 1);                                                    \
  PRIO(1); MFMAQ(0, 1, Ab, Bb); PRIO(0);                                       \
} while (0)

// ---- MFMA-first variant: same barriers/gates/staging, MFMA leads.
#define ITER_MF(T, SE, SO, GE, GO, LAST) do {                                  \
  /* even tile: slot0 */                                                       \
  PRIO(1); MFMAQ(0, 0, Aa, Ba); PRIO(0);                                       \
  RD_A(Ab, aS0, 2);                                                            \
  PRIO(1); MFMAQ(2, 0, Ab, Ba); PRIO(0);                                       \
  RD_B(Bb, bS0, 1);                                                            \
  BAR();                                                                       \
  PRIO(1); MFMAQ(2, 1, Ab, Bb); PRIO(0);                                       \
  if (SE) ST_A((T) + 2, 0);                                                    \
  GATE(GE); BAR();                                                             \
  PRIO(1); MFMAQ(0, 1, Aa, Bb); PRIO(0);                                       \
  RD_A(Ab, aS1, 0); RD_B(Ba, bS1, 0);                                          \
  if (SE) ST_B((T) + 2, 0);                                                    \
  /* odd tile: slot1 */                                                        \
  PRIO(1); MFMAQ(0, 0, Ab, Ba); PRIO(0);                                       \
  RD_A(Aa, aS1, 2);                                                            \
  PRIO(1); MFMAQ(2, 0, Aa, Ba); PRIO(0);                                       \
  RD_B(Bb, bS1, 1);                                                            \
  BAR();                                                                       \
  PRIO(1); MFMAQ(2, 1, Aa, Bb); PRIO(0);                                       \
  if (SO) ST_A((T) + 3, 1);                                                    \
  GATE(GO); BAR();                                                             \
  PRIO(1); MFMAQ(0, 1, Ab, Bb); PRIO(0);                                       \
  if (!LAST) { RD_A(Aa, aS0, 0); RD_B(Ba, bS0, 0); }                           \
  if (SO) ST_B((T) + 3, 1);                                                    \
} while (0)

__global__ __launch_bounds__(512, 2) void upconv_gemm(
    const __hip_bfloat16* __restrict__ xpad,   // [8][34][34][512]
    const __hip_bfloat16* __restrict__ weff,   // [4][512][2048]
    const float* __restrict__ bias,
    float* __restrict__ out) {                 // [8][512][64][64]
  extern __shared__ __align__(16) char lds[]; // 131072 B

  // px-twin XCD map (unchanged).
  const int bid = blockIdx.x;
  const int g = bid & 7, i = bid >> 3;
  const int py = g >> 2;
  const int mt = (g >> 1) & 1;
  const int nh = g & 1;
  const int px = i & 1;
  const int nt = nh * 16 + (i >> 1);   // 0..31
  const int p  = py * 2 + px;
  const int co0 = mt << 8;
  const int n0  = nt << 8;
  const int b   = n0 >> 10;
  const int rb  = (n0 & 1023) >> 5;    // 0,8,16,24

  const int tid  = threadIdx.x;
  const int lane = tid & 63;
  const int wv   = tid >> 6;           // 0..7
  const int wr   = wv >> 2;            // M half; also phase-skew selector
  const int wc   = wv & 3;             // N quarter (64 cols)

  // ---- staging (unchanged): row srow of each 128-row half, phys slot tid&7,
  // logical k-chunk sl = (tid&7)^(srow&7).
  const int srow = tid >> 3;           // 0..63
  const int sl   = (tid & 7) ^ (srow & 7);
  const int dA   = wv * 1024;

  const __hip_bfloat16* wpp = weff + ((size_t)p << 20);
  const __hip_bfloat16* pA0 = wpp + (size_t)(co0 + srow) * 2048 + sl * 8;
  const __hip_bfloat16* pB00 = xpad +
      ((size_t)(b * 34 + rb + (srow >> 5) + py) * 34 + (srow & 31) + px) * 512 + sl * 8;
  const __hip_bfloat16* pB01 = pB00 + (size_t)2 * 34 * 512;
  const __hip_bfloat16* pB10 = pB00 + (size_t)4 * 34 * 512;
  const __hip_bfloat16* pB11 = pB00 + (size_t)6 * 34 * 512;

  // ---- frag ds_read addressing for 32x32x16: lane -> row l&31 within a
  // 32-row block, k16-slot q -> logical 16B-slot q*2 + (l>>5), phys =
  // logical ^ (row&7) = ^ (l&7)  (block offsets are 32-multiples).
  int aq[4];
#pragma unroll
  for (int q = 0; q < 4; ++q)
    aq[q] = (lane & 31) * 128 + (((q * 2 + (lane >> 5)) ^ (lane & 7)) * 16);
  const char* aS0 = lds + wr * 16384;              // wave's 128 A rows (4 m32)
  const char* aS1 = aS0 + 32768;
  const char* bS0 = lds + 65536 + wc * 8192;       // wave's 64 B rows (2 n32)
  const char* bS1 = bS0 + 32768;

  f32x16 acc[4][2] = {};                // 128 VGPR
  bf16x8 Aa[8], Ab[8], Ba[4], Bb[4];    // 96 VGPR

  // ---- prologue: stage tiles 0,1; force tile 0; preload M0-1 / N0.
  ST_A(0, 0); ST_B(0, 0);
  ST_A(1, 1); ST_B(1, 1);
  GATE("8"); BAR();
  RD_A(Aa, aS0, 0); RD_B(Ba, bS0, 0);

  // ---- 16 iterations x 2 K-tiles = K 2048; wr selects the phase order.
  if (wr == 0) {
#pragma unroll 1
    for (int t = 0; t <= 28; t += 2) ITER_RF(t, true, true, "4", "4", false);
    ITER_RF(30, false, false, "0", "0", true);
  } else {
#pragma unroll 1
    for (int t = 0; t <= 28; t += 2) ITER_MF(t, true, true, "4", "4", false);
    ITER_MF(30, false, false, "0", "0", true);
  }

  // ---- epilogue: 32x32 D layout col=lane&31, row=(j&3)+8*(j>>2)+4*(lane>>5)
  // (m74/m101 verified).
#pragma unroll
  for (int M = 0; M < 4; ++M) {
    const int coM = co0 + wr * 128 + M * 32 + 4 * (lane >> 5);
#pragma unroll
    for (int N = 0; N < 2; ++N) {
      const int nl = wc * 64 + N * 32 + (lane & 31);
      const int rr = rb + (nl >> 5);
      const int ss = nl & 31;
      const int oh = rr * 2 + py;
      const int ow = ss * 2 + px;
#pragma unroll
      for (int j = 0; j < 16; ++j) {
        const int co = coM + (j & 3) + 8 * (j >> 2);
        out[(((size_t)(b * 512 + co) << 6) + oh) * 64 + ow] =
            acc[M][N][j] + bias[co];
      }
    }
  }
}

// ---------------------------------------------------------------------------
extern "C" void kernel_launch(void* const* d_in, const int* in_sizes, int n_in,
                              void* d_out, int out_size, void* d_ws, size_t ws_size,
                              hipStream_t stream) {
  (void)in_sizes; (void)n_in; (void)out_size; (void)ws_size;
  const float* x  = (const float*)d_in[0];   // [8][512][32][32]
  const float* w  = (const float*)d_in[1];   // [512][512][3][3]
  const float* bs = (const float*)d_in[2];   // [512]
  float* out = (float*)d_out;                // [8][512][64][64]
  char* ws = (char*)d_ws;
  __hip_bfloat16* xpad = (__hip_bfloat16*)ws;                 // 9,467,904 B
  __hip_bfloat16* weff = (__hip_bfloat16*)(ws + (10u << 20)); // 8,388,608 B
  fused_prep<<<dim3(3336), dim3(256), 0, stream>>>(x, w, xpad, weff);
  upconv_gemm<<<dim3(256), dim3(512), 131072, stream>>>(xpad, weff, bs, out);
}